// Round 6
// baseline (500.488 us; speedup 1.0000x reference)
//
#include <hip/hip_runtime.h>

typedef unsigned short u16;
typedef unsigned int   u32;
typedef __attribute__((ext_vector_type(8))) short bfrag;   // 8 x bf16
typedef __attribute__((ext_vector_type(4))) float ffrag;   // 4 x f32 acc

#define MFMA16(a,b,c) __builtin_amdgcn_mfma_f32_16x16x32_bf16((a),(b),(c),0,0,0)

// async global->LDS, 16B per lane; LDS dest = wave-uniform base + lane*16
#define GLL16(gp, lp) __builtin_amdgcn_global_load_lds( \
    (const __attribute__((address_space(1))) u32*)(gp), \
    (__attribute__((address_space(3))) u32*)(lp), 16, 0, 0)

__device__ __forceinline__ u16 f2b(float f) {          // fp32 -> bf16 RNE
  u32 u = __float_as_uint(f);
  return (u16)((u + 0x7fffu + ((u >> 16) & 1u)) >> 16);
}
__device__ __forceinline__ float b2f(u16 v) { return __uint_as_float(((u32)v) << 16); }

__device__ __forceinline__ void unpack8(uint4 q, u16 e[8]) {
  e[0] = q.x & 0xffffu; e[1] = q.x >> 16;
  e[2] = q.y & 0xffffu; e[3] = q.y >> 16;
  e[4] = q.z & 0xffffu; e[5] = q.z >> 16;
  e[6] = q.w & 0xffffu; e[7] = q.w >> 16;
}

// ---------------------------------------------------------------------------
// K0: fp32 -> bf16 conversion of x, Wk|Wv|Wr (stacked), Wo
// ---------------------------------------------------------------------------
__global__ __launch_bounds__(256) void cvt_all(
    const float* __restrict__ x,  const float* __restrict__ wk,
    const float* __restrict__ wv, const float* __restrict__ wr,
    const float* __restrict__ wo,
    u16* __restrict__ xb, u16* __restrict__ wb, u16* __restrict__ wob)
{
  size_t i4 = ((size_t)blockIdx.x * 256 + threadIdx.x) * 4;
  const float* src; u16* dst; size_t off;
  if      (i4 <  8388608) { src = x;  dst = xb;            off = i4; }
  else if (i4 <  9437184) { src = wk; dst = wb;            off = i4 - 8388608; }
  else if (i4 < 10485760) { src = wv; dst = wb + 1048576;  off = i4 - 9437184; }
  else if (i4 < 11534336) { src = wr; dst = wb + 2097152;  off = i4 - 10485760; }
  else                    { src = wo; dst = wob;           off = i4 - 11534336; }
  float4 f = *(const float4*)(src + off);
  u16 o[4] = { f2b(f.x), f2b(f.y), f2b(f.z), f2b(f.w) };
  *(ushort4*)(dst + off) = make_ushort4(o[0], o[1], o[2], o[3]);
}

// ---------------------------------------------------------------------------
// K1: fused k/v/r projection. M=8192, N=3072, K=1024.
// ROUND-10: RESIDENCY fix. r5-r9 showed neither LDS (512 cyc/iter) nor MFMA
// (620 cyc/iter) is saturated -- T_iter ~2000 cyc, Occupancy 31% (~1.25
// blocks/CU): the per-iter serial chain (barrier->wait->ds_read->MFMA) had
// no cross-block cover. Fix: double-buffer (48KB) so THREE blocks fit/CU
// (144<=160KB), requested via __launch_bounds__(512,6) (6 w/EU = 3 blocks
// of 8 waves). Grid 768 = exactly 3 resident blocks/CU, zero tail; each
// block's stalls covered by the other two.
// Wait ordering fixed (r9 had a cross-wave race): vmcnt BEFORE s_barrier --
// each wave proves its OWN stage(it) landed, barrier publishes to all;
// stage(it+1) issued after barrier (WAR: buf was last read at it-1, all
// waves past it-1's reads). Accumulation order unchanged (bitwise numerics).
// ---------------------------------------------------------------------------
__global__ __launch_bounds__(512, 6) void k1_proj(
    const u16* __restrict__ xb, const u16* __restrict__ wb,
    const float* __restrict__ tf,
    u16* __restrict__ kws, u16* __restrict__ vws, u16* __restrict__ rws)
{
  __shared__ u16 As[2][256 * 32];
  __shared__ u16 Bs[2][128 * 32];
  const int tid  = threadIdx.x;
  const int wave = tid >> 6, lane = tid & 63;
  const int li = lane & 15, quad = lane >> 4;
  const int wm = (wave >> 1) * 64, wn = (wave & 1) * 64;

  const int bid = blockIdx.x;
  const int xcd = bid & 7, j = bid >> 3;            // j in [0,96)
  const int n0 = (j >> 2) * 128;                    // 24 n-tiles
  const int m0 = ((xcd << 2) | (j & 3)) * 256;      // 4 m-tiles per XCD

  ffrag acc[4][4];
#pragma unroll
  for (int i = 0; i < 4; ++i)
#pragma unroll
    for (int jj = 0; jj < 4; ++jj)
#pragma unroll
      for (int r = 0; r < 4; ++r) acc[i][jj][r] = 0.f;

  // staging: A rows wave*32 + {0,16} + (lane>>2); B rows wave*16 + (lane>>2)
  const int sr = lane >> 2, sc = (lane & 3) * 8;
  const u16* ga0 = xb + (size_t)(m0 + wave * 32 + sr) * 1024 + sc;
  const u16* gb0 = wb + (size_t)(n0 + wave * 16 + sr) * 1024 + sc;

#define STG(IT, BF) do { \
    const u16* ga_ = ga0 + (IT) * 32; \
    const u16* gb_ = gb0 + (IT) * 32; \
    GLL16(ga_,             As[BF] + wave * 1024); \
    GLL16(ga_ + 16 * 1024, As[BF] + wave * 1024 + 512); \
    GLL16(gb_,             Bs[BF] + wave * 512); \
  } while (0)

  STG(0, 0);

  for (int it = 0; it < 32; ++it) {
    // own stage(it) landed (issued at it-1: ~1 compute phase of cover)
    asm volatile("s_waitcnt vmcnt(0)" ::: "memory");
    __builtin_amdgcn_sched_barrier(0);
    __builtin_amdgcn_s_barrier();     // => ALL waves' stage(it) landed;
    __builtin_amdgcn_sched_barrier(0);//    all reads of it-1 done (WAR)
    if (it + 1 < 32) STG(it + 1, (it + 1) & 1);

    const int cb = it & 1;
    bfrag av[4], bv[4];
#pragma unroll
    for (int i = 0; i < 4; ++i)  av[i]  = *(const bfrag*)&As[cb][(wm + i * 16 + li) * 32 + quad * 8];
#pragma unroll
    for (int jj = 0; jj < 4; ++jj) bv[jj] = *(const bfrag*)&Bs[cb][(wn + jj * 16 + li) * 32 + quad * 8];
#pragma unroll
    for (int i = 0; i < 4; ++i)
#pragma unroll
      for (int jj = 0; jj < 4; ++jj)
        acc[i][jj] = MFMA16(av[i], bv[jj], acc[i][jj]);
  }
#undef STG

  const int sel = n0 >> 10;   // uniform per block
#pragma unroll
  for (int i = 0; i < 4; ++i) {
#pragma unroll
    for (int jj = 0; jj < 4; ++jj) {
#pragma unroll
      for (int r = 0; r < 4; ++r) {
        int m = m0 + wm + i * 16 + quad * 4 + r;       // row = b*2048 + l
        int n = n0 + wn + jj * 16 + li;
        int c = n & 1023;                               // h*64 + d
        int bb = m >> 11, l = m & 2047;
        size_t dst = (size_t)((bb << 4) | (c >> 6)) * 131072 + (size_t)l * 64 + (c & 63);
        float v = acc[i][jj][r];
        if (sel == 0)      kws[dst] = f2b(v * tf[c]);                 // fold time_first into k
        else if (sel == 1) vws[dst] = f2b(v);
        else               rws[dst] = f2b(1.f / (1.f + __expf(-v)));  // sigmoid
      }
    }
  }
}

// ---------------------------------------------------------------------------
// RWKV chunked recurrence, de-serialized into 3 parallel kernels.
// K2a: per (b,h,chunk) block, U^T[e][d] = sum_s V[s,e] * Ktf[s,d]*Dh^(63-s)
// K2b: scan S_{c+1} = Dh^64 S_c + U_c (fp32 acc), store S^T per chunk (bf16)
// K2c: Y = masked(R@Ktf^T)@V + Dh^(t+1) * (R @ S_c^T)
// ---------------------------------------------------------------------------
#define ST 72

__global__ __launch_bounds__(256) void k2a_u(
    const u16* __restrict__ kws, const u16* __restrict__ vws,
    const float* __restrict__ td, u16* __restrict__ ut)
{
  __shared__ u16 KbarT[64 * ST];  // [d][s], scaled by Dh^(63-s)
  __shared__ u16 Vt[64 * ST];     // [e][s]
  const int tid = threadIdx.x;
  const int lane = tid & 63, wave = tid >> 6;
  const int li = lane & 15, quad = lane >> 4;
  const int wr = (wave >> 1) * 32, wc = (wave & 1) * 32;
  const int bid = blockIdx.x;
  const int bh = bid >> 5, ch = bid & 31;
  const int h = bh & 15;
  const float l2D = log2f(td[h * 64]);
  const size_t base = (size_t)bh * 131072 + (size_t)ch * 4096;

#pragma unroll
  for (int it = 0; it < 2; ++it) {
    int c16 = tid + it * 256;
    int row = c16 >> 3, c8 = (c16 & 7) * 8;
    size_t g = base + (size_t)row * 64 + c8;
    uint4 kq = *(const uint4*)(kws + g);
    u16 ke[8]; unpack8(kq, ke);
    float sk = exp2f((float)(63 - row) * l2D);
#pragma unroll
    for (int jj = 0; jj < 8; ++jj) KbarT[(c8 + jj) * ST + row] = f2b(b2f(ke[jj]) * sk);
    uint4 vq = *(const uint4*)(vws + g);
    u16 ve[8]; unpack8(vq, ve);
#pragma unroll
    for (int jj = 0; jj < 8; ++jj) Vt[(c8 + jj) * ST + row] = ve[jj];
  }
  __syncthreads();

  ffrag U[2][2];
#pragma unroll
  for (int a = 0; a < 2; ++a)
#pragma unroll
    for (int b = 0; b < 2; ++b)
#pragma unroll
      for (int r = 0; r < 4; ++r) U[a][b][r] = 0.f;
#pragma unroll
  for (int kk = 0; kk < 64; kk += 32) {
    bfrag a0 = *(const bfrag*)&Vt[(wr + li) * ST + kk + quad * 8];
    bfrag a1 = *(const bfrag*)&Vt[(wr + 16 + li) * ST + kk + quad * 8];
    bfrag b0 = *(const bfrag*)&KbarT[(wc + li) * ST + kk + quad * 8];
    bfrag b1 = *(const bfrag*)&KbarT[(wc + 16 + li) * ST + kk + quad * 8];
    U[0][0] = MFMA16(a0, b0, U[0][0]);
    U[0][1] = MFMA16(a0, b1, U[0][1]);
    U[1][0] = MFMA16(a1, b0, U[1][0]);
    U[1][1] = MFMA16(a1, b1, U[1][1]);
  }

  u16* dst = ut + ((size_t)bid << 12);   // [bh][ch][e][d], bf16
#pragma unroll
  for (int ti = 0; ti < 2; ++ti)
#pragma unroll
    for (int tj = 0; tj < 2; ++tj)
#pragma unroll
      for (int r = 0; r < 4; ++r) {
        int e = wr + ti * 16 + quad * 4 + r;
        int d = wc + tj * 16 + li;
        dst[e * 64 + d] = f2b(U[ti][tj][r]);
      }
}

__global__ __launch_bounds__(256) void k2b_scan(
    const u16* __restrict__ ut, const float* __restrict__ td,
    u16* __restrict__ sbf, float* __restrict__ fstate)
{
  __shared__ float Sl[4 * 65];
  const int tid = threadIdx.x;
  const int bid = blockIdx.x;
  const int bh = bid >> 4, q = bid & 15;       // q: which 256-slice of ed
  const int ed = q * 256 + tid;                // ed = e*64 + d (transposed layout)
  const int h = bh & 15;
  const float Dh = td[h * 64];
  const float DhC = exp2f(64.f * log2f(Dh));

  float S = 0.f;
  size_t idx = ((size_t)bh * 32) * 4096 + ed;
  for (int c = 0; c < 32; ++c, idx += 4096) {
    sbf[idx] = f2b(S);             // state at START of chunk c
    S = S * DhC + b2f(ut[idx]);
  }
  // final state: transpose [e][d] -> [d][e] via LDS
  Sl[(tid >> 6) * 65 + (tid & 63)] = S;   // e = q*4 + (tid>>6), d = tid&63
  __syncthreads();
  int d = tid >> 2, el = tid & 3;
  fstate[(size_t)bh * 4096 + (size_t)d * 64 + q * 4 + el] = Sl[el * 65 + d];
}

__global__ __launch_bounds__(256) void k2c_y(
    const u16* __restrict__ kws, const u16* __restrict__ vws, const u16* __restrict__ rws,
    const u16* __restrict__ sbf, const float* __restrict__ td,
    u16* __restrict__ yws)
{
  __shared__ u16 Rc[64 * ST];     // R natural [t][d]
  __shared__ u16 KcA[64 * ST];    // Ktf natural [s][d]; reused as Abuf [t][s]
  __shared__ u16 Vt[64 * ST];     // V^T [e][s]
  __shared__ u16 STc[64 * ST];    // S^T chunk [e][d]
  __shared__ float Dpow[65];

  const int tid = threadIdx.x;
  const int lane = tid & 63, wave = tid >> 6;
  const int li = lane & 15, quad = lane >> 4;
  const int wr = (wave >> 1) * 32, wc = (wave & 1) * 32;
  const int bid = blockIdx.x;
  const int bh = bid >> 5, ch = bid & 31;
  const int h = bh & 15, bb = bh >> 4;
  const float l2D = log2f(td[h * 64]);
  if (tid <= 64) Dpow[tid] = exp2f((float)tid * l2D);

  const size_t base = (size_t)bh * 131072 + (size_t)ch * 4096;
  const u16* sp = sbf + ((size_t)bid << 12);

#pragma unroll
  for (int it = 0; it < 2; ++it) {
    int c16 = tid + it * 256;
    int row = c16 >> 3, c8 = (c16 & 7) * 8;
    size_t g = base + (size_t)row * 64 + c8;
    *(uint4*)&Rc[row * ST + c8]  = *(const uint4*)(rws + g);
    *(uint4*)&KcA[row * ST + c8] = *(const uint4*)(kws + g);
    *(uint4*)&STc[row * ST + c8] = *(const uint4*)(sp + (size_t)row * 64 + c8);
    uint4 vq = *(const uint4*)(vws + g);
    u16 ve[8]; unpack8(vq, ve);
#pragma unroll
    for (int jj = 0; jj < 8; ++jj) Vt[(c8 + jj) * ST + row] = ve[jj];
  }
  __syncthreads();   // B1

  ffrag P[2][2], Y[2][2];
#pragma unroll
  for (int a = 0; a < 2; ++a)
#pragma unroll
    for (int b = 0; b < 2; ++b)
#pragma unroll
      for (int r = 0; r < 4; ++r) { P[a][b][r] = 0.f; Y[a][b][r] = 0.f; }

#pragma unroll
  for (int kk = 0; kk < 64; kk += 32) {
    bfrag a0 = *(const bfrag*)&Rc[(wr + li) * ST + kk + quad * 8];
    bfrag a1 = *(const bfrag*)&Rc[(wr + 16 + li) * ST + kk + quad * 8];
    bfrag b0 = *(const bfrag*)&KcA[(wc + li) * ST + kk + quad * 8];
    bfrag b1 = *(const bfrag*)&KcA[(wc + 16 + li) * ST + kk + quad * 8];
    P[0][0] = MFMA16(a0, b0, P[0][0]);
    P[0][1] = MFMA16(a0, b1, P[0][1]);
    P[1][0] = MFMA16(a1, b0, P[1][0]);
    P[1][1] = MFMA16(a1, b1, P[1][1]);
    bfrag s0 = *(const bfrag*)&STc[(wc + li) * ST + kk + quad * 8];
    bfrag s1 = *(const bfrag*)&STc[(wc + 16 + li) * ST + kk + quad * 8];
    Y[0][0] = MFMA16(a0, s0, Y[0][0]);
    Y[0][1] = MFMA16(a0, s1, Y[0][1]);
    Y[1][0] = MFMA16(a1, s0, Y[1][0]);
    Y[1][1] = MFMA16(a1, s1, Y[1][1]);
  }

  // row-scale the R@S^T partial by Dh^(t+1) (commutes: scale is per output row)
#pragma unroll
  for (int ti = 0; ti < 2; ++ti)
#pragma unroll
    for (int tj = 0; tj < 2; ++tj)
#pragma unroll
      for (int r = 0; r < 4; ++r) {
        int t = wr + ti * 16 + quad * 4 + r;
        Y[ti][tj][r] *= Dpow[t + 1];
      }
  __syncthreads();   // Bmid: everyone done reading KcA (Ktf)

  // masked decay-scaled A -> Abuf (aliases KcA)
#pragma unroll
  for (int ti = 0; ti < 2; ++ti)
#pragma unroll
    for (int tj = 0; tj < 2; ++tj)
#pragma unroll
      for (int r = 0; r < 4; ++r) {
        int t = wr + ti * 16 + quad * 4 + r;
        int s = wc + tj * 16 + li;
        float v = (t >= s) ? P[ti][tj][r] * Dpow[t - s] : 0.f;
        KcA[t * ST + s] = f2b(v);
      }
  __syncthreads();   // B2: Abuf visible

#pragma unroll
  for (int kk = 0; kk < 64; kk += 32) {
    bfrag aa0 = *(const bfrag*)&KcA[(wr + li) * ST + kk + quad * 8];
    bfrag aa1 = *(const bfrag*)&KcA[(wr + 16 + li) * ST + kk + quad * 8];
    bfrag vb0 = *(const bfrag*)&Vt[(wc + li) * ST + kk + quad * 8];
    bfrag vb1 = *(const bfrag*)&Vt[(wc + 16 + li) * ST + kk + quad * 8];
    Y[0][0] = MFMA16(aa0, vb0, Y[0][0]);
    Y[0][1] = MFMA16(aa0, vb1, Y[0][1]);
    Y[1][0] = MFMA16(aa1, vb0, Y[1][0]);
    Y[1][1] = MFMA16(aa1, vb1, Y[1][1]);
  }

#pragma unroll
  for (int ti = 0; ti < 2; ++ti)
#pragma unroll
    for (int tj = 0; tj < 2; ++tj)
#pragma unroll
      for (int r = 0; r < 4; ++r) {
        int t = wr + ti * 16 + quad * 4 + r;
        int e = wc + tj * 16 + li;
        yws[((size_t)(bb * 2048 + ch * 64 + t)) * 1024 + h * 64 + e] = f2b(Y[ti][tj][r]);
      }
}

// ---------------------------------------------------------------------------
// K3: y = Y_rwkv @ Wo^T, M=8192, N=1024, K=1024.
// ROUND-10: tri-buffer kept (1 block/CU; deeper pipeline), but with the
// RACE-FREE ordering: vmcnt(3) BEFORE s_barrier (own stage(it) landed,
// stage(it+1) stays in flight), stage(it+2) after barrier.
// ---------------------------------------------------------------------------
__global__ __launch_bounds__(512, 4) void k3_out(
    const u16* __restrict__ yb, const u16* __restrict__ wob, float* __restrict__ out)
{
  __shared__ u16 As[3][256 * 32];
  __shared__ u16 Bs[3][128 * 32];
  const int tid  = threadIdx.x;
  const int wave = tid >> 6, lane = tid & 63;
  const int li = lane & 15, quad = lane >> 4;
  const int wm = (wave >> 1) * 64, wn = (wave & 1) * 64;

  const int bid = blockIdx.x;
  const int xcd = bid & 7, j = bid >> 3;            // j in [0,32)
  const int n0 = (j >> 2) * 128;                    // 8 n-tiles
  const int m0 = ((xcd << 2) | (j & 3)) * 256;      // 4 m-tiles per XCD

  ffrag acc[4][4];
#pragma unroll
  for (int i = 0; i < 4; ++i)
#pragma unroll
    for (int jj = 0; jj < 4; ++jj)
#pragma unroll
      for (int r = 0; r < 4; ++r) acc[i][jj][r] = 0.f;

  const int sr = lane >> 2, sc = (lane & 3) * 8;
  const u16* ga0 = yb  + (size_t)(m0 + wave * 32 + sr) * 1024 + sc;
  const u16* gb0 = wob + (size_t)(n0 + wave * 16 + sr) * 1024 + sc;

#define STG(IT, BF) do { \
    const u16* ga_ = ga0 + (IT) * 32; \
    const u16* gb_ = gb0 + (IT) * 32; \
    GLL16(ga_,             As[BF] + wave * 1024); \
    GLL16(ga_ + 16 * 1024, As[BF] + wave * 1024 + 512); \
    GLL16(gb_,             Bs[BF] + wave * 512); \
  } while (0)

  STG(0, 0);
  STG(1, 1);

  int cb = 0, sb = 2;
  for (int it = 0; it < 32; ++it) {
    if (it < 31) { asm volatile("s_waitcnt vmcnt(3)" ::: "memory"); }
    else         { asm volatile("s_waitcnt vmcnt(0)" ::: "memory"); }
    __builtin_amdgcn_sched_barrier(0);
    __builtin_amdgcn_s_barrier();      // all waves' stage(it) landed
    __builtin_amdgcn_sched_barrier(0);
    if (it + 2 < 32) STG(it + 2, sb);

    bfrag av[4], bv[4];
#pragma unroll
    for (int i = 0; i < 4; ++i)  av[i]  = *(const bfrag*)&As[cb][(wm + i * 16 + li) * 32 + quad * 8];
#pragma unroll
    for (int jj = 0; jj < 4; ++jj) bv[jj] = *(const bfrag*)&Bs[cb][(wn + jj * 16 + li) * 32 + quad * 8];
#pragma unroll
    for (int i = 0; i < 4; ++i)
#pragma unroll
      for (int jj = 0; jj < 4; ++jj)
        acc[i][jj] = MFMA16(av[i], bv[jj], acc[i][jj]);

    cb = (cb == 2) ? 0 : cb + 1;
    sb = (sb == 2) ? 0 : sb + 1;
  }
#undef STG

#pragma unroll
  for (int i = 0; i < 4; ++i)
#pragma unroll
    for (int jj = 0; jj < 4; ++jj)
#pragma unroll
      for (int r = 0; r < 4; ++r) {
        int m = m0 + wm + i * 16 + quad * 4 + r;
        int n = n0 + wn + jj * 16 + li;
        out[(size_t)m * 1024 + n] = acc[i][jj][r];
      }
}

// ---------------------------------------------------------------------------
// Workspace layout (u16 elements):
//   xb   @ 0          (8388608)   -- reused as yws after K1
//   wb   @ 8388608    (3145728)
//   wob  @ 11534336   (1048576)
//   kws  @ 12582912   (8388608)   (B,H,L,HD) k*tf
//   vws  @ 20971520   (8388608)
//   rws  @ 29360128   (8388608)   sigmoid applied
//   ut   @ 37748736   (8388608)   U^T per (bh,chunk), bf16
//   sbf  @ 54525952   (8388608)   S^T per (bh,chunk), bf16
// ---------------------------------------------------------------------------
extern "C" void kernel_launch(void* const* d_in, const int* in_sizes, int n_in,
                              void* d_out, int out_size, void* d_ws, size_t ws_size,
                              hipStream_t stream) {
  const float* x  = (const float*)d_in[0];
  const float* Wk = (const float*)d_in[1];
  const float* Wv = (const float*)d_in[2];
  const float* Wr = (const float*)d_in[3];
  const float* Wo = (const float*)d_in[4];
  const float* td = (const float*)d_in[5];
  const float* tf = (const float*)d_in[6];
  float* out = (float*)d_out;

  u16* ws  = (u16*)d_ws;
  u16* xb  = ws;
  u16* wb  = ws + 8388608;
  u16* wob = ws + 11534336;
  u16* kws = ws + 12582912;
  u16* vws = ws + 20971520;
  u16* rws = ws + 29360128;
  u16* ut  = ws + 37748736;
  u16* sbf = ws + 54525952;
  u16* yws = xb;   // xb dead after K1

  hipLaunchKernelGGL(cvt_all, dim3(12288), dim3(256), 0, stream,
                     x, Wk, Wv, Wr, Wo, xb, wb, wob);
  hipLaunchKernelGGL(k1_proj, dim3(768), dim3(512), 0, stream,
                     xb, wb, tf, kws, vws, rws);
  hipLaunchKernelGGL(k2a_u, dim3(2048), dim3(256), 0, stream,
                     kws, vws, td, ut);
  hipLaunchKernelGGL(k2b_scan, dim3(1024), dim3(256), 0, stream,
                     ut, td, sbf, out + 8388608);
  hipLaunchKernelGGL(k2c_y, dim3(2048), dim3(256), 0, stream,
                     kws, vws, rws, sbf, td, yws);
  hipLaunchKernelGGL(k3_out, dim3(256), dim3(512), 0, stream,
                     yws, wob, out);
}

// Round 7
// 229.388 us; speedup vs baseline: 2.1818x; 2.1818x over previous
//
#include <hip/hip_runtime.h>

typedef unsigned short u16;
typedef unsigned int   u32;
typedef __attribute__((ext_vector_type(8))) short bfrag;   // 8 x bf16
typedef __attribute__((ext_vector_type(4))) float ffrag;   // 4 x f32 acc

#define MFMA16(a,b,c) __builtin_amdgcn_mfma_f32_16x16x32_bf16((a),(b),(c),0,0,0)

// async global->LDS, 16B per lane; LDS dest = wave-uniform base + lane*16
#define GLL16(gp, lp) __builtin_amdgcn_global_load_lds( \
    (const __attribute__((address_space(1))) u32*)(gp), \
    (__attribute__((address_space(3))) u32*)(lp), 16, 0, 0)

__device__ __forceinline__ u16 f2b(float f) {          // fp32 -> bf16 RNE
  u32 u = __float_as_uint(f);
  return (u16)((u + 0x7fffu + ((u >> 16) & 1u)) >> 16);
}
__device__ __forceinline__ float b2f(u16 v) { return __uint_as_float(((u32)v) << 16); }

__device__ __forceinline__ void unpack8(uint4 q, u16 e[8]) {
  e[0] = q.x & 0xffffu; e[1] = q.x >> 16;
  e[2] = q.y & 0xffffu; e[3] = q.y >> 16;
  e[4] = q.z & 0xffffu; e[5] = q.z >> 16;
  e[6] = q.w & 0xffffu; e[7] = q.w >> 16;
}

// ---------------------------------------------------------------------------
// K0: fp32 -> bf16 conversion of x, Wk|Wv|Wr (stacked), Wo
// ---------------------------------------------------------------------------
__global__ __launch_bounds__(256) void cvt_all(
    const float* __restrict__ x,  const float* __restrict__ wk,
    const float* __restrict__ wv, const float* __restrict__ wr,
    const float* __restrict__ wo,
    u16* __restrict__ xb, u16* __restrict__ wb, u16* __restrict__ wob)
{
  size_t i4 = ((size_t)blockIdx.x * 256 + threadIdx.x) * 4;
  const float* src; u16* dst; size_t off;
  if      (i4 <  8388608) { src = x;  dst = xb;            off = i4; }
  else if (i4 <  9437184) { src = wk; dst = wb;            off = i4 - 8388608; }
  else if (i4 < 10485760) { src = wv; dst = wb + 1048576;  off = i4 - 9437184; }
  else if (i4 < 11534336) { src = wr; dst = wb + 2097152;  off = i4 - 10485760; }
  else                    { src = wo; dst = wob;           off = i4 - 11534336; }
  float4 f = *(const float4*)(src + off);
  u16 o[4] = { f2b(f.x), f2b(f.y), f2b(f.z), f2b(f.w) };
  *(ushort4*)(dst + off) = make_ushort4(o[0], o[1], o[2], o[3]);
}

// ---------------------------------------------------------------------------
// K1: fused k/v/r projection. M=8192, N=3072, K=1024.
// ROUND-11: m97/m103 PROVEN geometry -- 128x128 tile, 256 thr (4 waves,
// 64x64 each), BK=32 dbuf (32KB LDS), GLL16 width-16 staging, plain
// __syncthreads 2-phase loop. learn_hip tile-space AT THIS STRUCTURE
// (ref-checked, 4096^3): 128^2=912 TF > 128x256=823 (round-0's shape) >
// 256^2=792. 32KB LDS + ~52 VGPR -> 4 blocks/CU resident (16 waves), twice
// round-0's cross-block barrier cover. launch_bounds(256,4): budget 128
// VGPR >> 52 used -- no spill (round-6 lesson: (512,6) forced 85-reg cap
// -> acc spilled to scratch -> 873MB writes, 4x slower).
// Grid 1536 = 64 m-tiles x 24 n-tiles; XCD chunking: 8 m-tiles/XCD, m
// fastest. Accumulation order per output unchanged (bitwise numerics).
// ---------------------------------------------------------------------------
__global__ __launch_bounds__(256, 4) void k1_proj(
    const u16* __restrict__ xb, const u16* __restrict__ wb,
    const float* __restrict__ tf,
    u16* __restrict__ kws, u16* __restrict__ vws, u16* __restrict__ rws)
{
  __shared__ u16 As[2][128 * 32];
  __shared__ u16 Bs[2][128 * 32];
  const int tid  = threadIdx.x;
  const int wave = tid >> 6, lane = tid & 63;
  const int li = lane & 15, quad = lane >> 4;
  const int wm = (wave >> 1) * 64, wn = (wave & 1) * 64;

  const int bid = blockIdx.x;
  const int xcd = bid & 7, j = bid >> 3;            // j in [0,192)
  const int m0 = ((xcd << 3) | (j & 7)) * 128;      // 64 m-tiles, 8 per XCD
  const int n0 = (j >> 3) * 128;                    // 24 n-tiles

  ffrag acc[4][4];
#pragma unroll
  for (int i = 0; i < 4; ++i)
#pragma unroll
    for (int jj = 0; jj < 4; ++jj)
#pragma unroll
      for (int r = 0; r < 4; ++r) acc[i][jj][r] = 0.f;

  // staging: per wave 32 rows of A and B (2 GLLs each: rows +0 / +16)
  const int sr = lane >> 2, sc = (lane & 3) * 8;
  const u16* ga0 = xb + (size_t)(m0 + wave * 32 + sr) * 1024 + sc;
  const u16* gb0 = wb + (size_t)(n0 + wave * 32 + sr) * 1024 + sc;

#define STG(IT, BF) do { \
    const u16* ga_ = ga0 + (IT) * 32; \
    const u16* gb_ = gb0 + (IT) * 32; \
    GLL16(ga_,             As[BF] + wave * 1024); \
    GLL16(ga_ + 16 * 1024, As[BF] + wave * 1024 + 512); \
    GLL16(gb_,             Bs[BF] + wave * 1024); \
    GLL16(gb_ + 16 * 1024, Bs[BF] + wave * 1024 + 512); \
  } while (0)

  STG(0, 0);

  for (int it = 0; it < 32; ++it) {
    __syncthreads();   // drains own vmcnt then barriers: stage(it) visible
    if (it + 1 < 32) STG(it + 1, (it + 1) & 1);

    const int cb = it & 1;
    bfrag av[4], bv[4];
#pragma unroll
    for (int i = 0; i < 4; ++i)  av[i]  = *(const bfrag*)&As[cb][(wm + i * 16 + li) * 32 + quad * 8];
#pragma unroll
    for (int jj = 0; jj < 4; ++jj) bv[jj] = *(const bfrag*)&Bs[cb][(wn + jj * 16 + li) * 32 + quad * 8];
#pragma unroll
    for (int i = 0; i < 4; ++i)
#pragma unroll
      for (int jj = 0; jj < 4; ++jj)
        acc[i][jj] = MFMA16(av[i], bv[jj], acc[i][jj]);
  }
#undef STG

  const int sel = n0 >> 10;   // uniform per block
#pragma unroll
  for (int i = 0; i < 4; ++i) {
#pragma unroll
    for (int jj = 0; jj < 4; ++jj) {
#pragma unroll
      for (int r = 0; r < 4; ++r) {
        int m = m0 + wm + i * 16 + quad * 4 + r;       // row = b*2048 + l
        int n = n0 + wn + jj * 16 + li;
        int c = n & 1023;                               // h*64 + d
        int bb = m >> 11, l = m & 2047;
        size_t dst = (size_t)((bb << 4) | (c >> 6)) * 131072 + (size_t)l * 64 + (c & 63);
        float v = acc[i][jj][r];
        if (sel == 0)      kws[dst] = f2b(v * tf[c]);                 // fold time_first into k
        else if (sel == 1) vws[dst] = f2b(v);
        else               rws[dst] = f2b(1.f / (1.f + __expf(-v)));  // sigmoid
      }
    }
  }
}

// ---------------------------------------------------------------------------
// RWKV chunked recurrence, de-serialized into 3 parallel kernels.
// K2a: per (b,h,chunk) block, U^T[e][d] = sum_s V[s,e] * Ktf[s,d]*Dh^(63-s)
// K2b: scan S_{c+1} = Dh^64 S_c + U_c (fp32 acc), store S^T per chunk (bf16)
// K2c: Y = masked(R@Ktf^T)@V + Dh^(t+1) * (R @ S_c^T)
// ---------------------------------------------------------------------------
#define ST 72

__global__ __launch_bounds__(256) void k2a_u(
    const u16* __restrict__ kws, const u16* __restrict__ vws,
    const float* __restrict__ td, u16* __restrict__ ut)
{
  __shared__ u16 KbarT[64 * ST];  // [d][s], scaled by Dh^(63-s)
  __shared__ u16 Vt[64 * ST];     // [e][s]
  const int tid = threadIdx.x;
  const int lane = tid & 63, wave = tid >> 6;
  const int li = lane & 15, quad = lane >> 4;
  const int wr = (wave >> 1) * 32, wc = (wave & 1) * 32;
  const int bid = blockIdx.x;
  const int bh = bid >> 5, ch = bid & 31;
  const int h = bh & 15;
  const float l2D = log2f(td[h * 64]);
  const size_t base = (size_t)bh * 131072 + (size_t)ch * 4096;

#pragma unroll
  for (int it = 0; it < 2; ++it) {
    int c16 = tid + it * 256;
    int row = c16 >> 3, c8 = (c16 & 7) * 8;
    size_t g = base + (size_t)row * 64 + c8;
    uint4 kq = *(const uint4*)(kws + g);
    u16 ke[8]; unpack8(kq, ke);
    float sk = exp2f((float)(63 - row) * l2D);
#pragma unroll
    for (int jj = 0; jj < 8; ++jj) KbarT[(c8 + jj) * ST + row] = f2b(b2f(ke[jj]) * sk);
    uint4 vq = *(const uint4*)(vws + g);
    u16 ve[8]; unpack8(vq, ve);
#pragma unroll
    for (int jj = 0; jj < 8; ++jj) Vt[(c8 + jj) * ST + row] = ve[jj];
  }
  __syncthreads();

  ffrag U[2][2];
#pragma unroll
  for (int a = 0; a < 2; ++a)
#pragma unroll
    for (int b = 0; b < 2; ++b)
#pragma unroll
      for (int r = 0; r < 4; ++r) U[a][b][r] = 0.f;
#pragma unroll
  for (int kk = 0; kk < 64; kk += 32) {
    bfrag a0 = *(const bfrag*)&Vt[(wr + li) * ST + kk + quad * 8];
    bfrag a1 = *(const bfrag*)&Vt[(wr + 16 + li) * ST + kk + quad * 8];
    bfrag b0 = *(const bfrag*)&KbarT[(wc + li) * ST + kk + quad * 8];
    bfrag b1 = *(const bfrag*)&KbarT[(wc + 16 + li) * ST + kk + quad * 8];
    U[0][0] = MFMA16(a0, b0, U[0][0]);
    U[0][1] = MFMA16(a0, b1, U[0][1]);
    U[1][0] = MFMA16(a1, b0, U[1][0]);
    U[1][1] = MFMA16(a1, b1, U[1][1]);
  }

  u16* dst = ut + ((size_t)bid << 12);   // [bh][ch][e][d], bf16
#pragma unroll
  for (int ti = 0; ti < 2; ++ti)
#pragma unroll
    for (int tj = 0; tj < 2; ++tj)
#pragma unroll
      for (int r = 0; r < 4; ++r) {
        int e = wr + ti * 16 + quad * 4 + r;
        int d = wc + tj * 16 + li;
        dst[e * 64 + d] = f2b(U[ti][tj][r]);
      }
}

__global__ __launch_bounds__(256) void k2b_scan(
    const u16* __restrict__ ut, const float* __restrict__ td,
    u16* __restrict__ sbf, float* __restrict__ fstate)
{
  __shared__ float Sl[4 * 65];
  const int tid = threadIdx.x;
  const int bid = blockIdx.x;
  const int bh = bid >> 4, q = bid & 15;       // q: which 256-slice of ed
  const int ed = q * 256 + tid;                // ed = e*64 + d (transposed layout)
  const int h = bh & 15;
  const float Dh = td[h * 64];
  const float DhC = exp2f(64.f * log2f(Dh));

  float S = 0.f;
  size_t idx = ((size_t)bh * 32) * 4096 + ed;
  for (int c = 0; c < 32; ++c, idx += 4096) {
    sbf[idx] = f2b(S);             // state at START of chunk c
    S = S * DhC + b2f(ut[idx]);
  }
  // final state: transpose [e][d] -> [d][e] via LDS
  Sl[(tid >> 6) * 65 + (tid & 63)] = S;   // e = q*4 + (tid>>6), d = tid&63
  __syncthreads();
  int d = tid >> 2, el = tid & 3;
  fstate[(size_t)bh * 4096 + (size_t)d * 64 + q * 4 + el] = Sl[el * 65 + d];
}

__global__ __launch_bounds__(256) void k2c_y(
    const u16* __restrict__ kws, const u16* __restrict__ vws, const u16* __restrict__ rws,
    const u16* __restrict__ sbf, const float* __restrict__ td,
    u16* __restrict__ yws)
{
  __shared__ u16 Rc[64 * ST];     // R natural [t][d]
  __shared__ u16 KcA[64 * ST];    // Ktf natural [s][d]; reused as Abuf [t][s]
  __shared__ u16 Vt[64 * ST];     // V^T [e][s]
  __shared__ u16 STc[64 * ST];    // S^T chunk [e][d]
  __shared__ float Dpow[65];

  const int tid = threadIdx.x;
  const int lane = tid & 63, wave = tid >> 6;
  const int li = lane & 15, quad = lane >> 4;
  const int wr = (wave >> 1) * 32, wc = (wave & 1) * 32;
  const int bid = blockIdx.x;
  const int bh = bid >> 5, ch = bid & 31;
  const int h = bh & 15, bb = bh >> 4;
  const float l2D = log2f(td[h * 64]);
  if (tid <= 64) Dpow[tid] = exp2f((float)tid * l2D);

  const size_t base = (size_t)bh * 131072 + (size_t)ch * 4096;
  const u16* sp = sbf + ((size_t)bid << 12);

#pragma unroll
  for (int it = 0; it < 2; ++it) {
    int c16 = tid + it * 256;
    int row = c16 >> 3, c8 = (c16 & 7) * 8;
    size_t g = base + (size_t)row * 64 + c8;
    *(uint4*)&Rc[row * ST + c8]  = *(const uint4*)(rws + g);
    *(uint4*)&KcA[row * ST + c8] = *(const uint4*)(kws + g);
    *(uint4*)&STc[row * ST + c8] = *(const uint4*)(sp + (size_t)row * 64 + c8);
    uint4 vq = *(const uint4*)(vws + g);
    u16 ve[8]; unpack8(vq, ve);
#pragma unroll
    for (int jj = 0; jj < 8; ++jj) Vt[(c8 + jj) * ST + row] = ve[jj];
  }
  __syncthreads();   // B1

  ffrag P[2][2], Y[2][2];
#pragma unroll
  for (int a = 0; a < 2; ++a)
#pragma unroll
    for (int b = 0; b < 2; ++b)
#pragma unroll
      for (int r = 0; r < 4; ++r) { P[a][b][r] = 0.f; Y[a][b][r] = 0.f; }

#pragma unroll
  for (int kk = 0; kk < 64; kk += 32) {
    bfrag a0 = *(const bfrag*)&Rc[(wr + li) * ST + kk + quad * 8];
    bfrag a1 = *(const bfrag*)&Rc[(wr + 16 + li) * ST + kk + quad * 8];
    bfrag b0 = *(const bfrag*)&KcA[(wc + li) * ST + kk + quad * 8];
    bfrag b1 = *(const bfrag*)&KcA[(wc + 16 + li) * ST + kk + quad * 8];
    P[0][0] = MFMA16(a0, b0, P[0][0]);
    P[0][1] = MFMA16(a0, b1, P[0][1]);
    P[1][0] = MFMA16(a1, b0, P[1][0]);
    P[1][1] = MFMA16(a1, b1, P[1][1]);
    bfrag s0 = *(const bfrag*)&STc[(wc + li) * ST + kk + quad * 8];
    bfrag s1 = *(const bfrag*)&STc[(wc + 16 + li) * ST + kk + quad * 8];
    Y[0][0] = MFMA16(a0, s0, Y[0][0]);
    Y[0][1] = MFMA16(a0, s1, Y[0][1]);
    Y[1][0] = MFMA16(a1, s0, Y[1][0]);
    Y[1][1] = MFMA16(a1, s1, Y[1][1]);
  }

  // row-scale the R@S^T partial by Dh^(t+1) (commutes: scale is per output row)
#pragma unroll
  for (int ti = 0; ti < 2; ++ti)
#pragma unroll
    for (int tj = 0; tj < 2; ++tj)
#pragma unroll
      for (int r = 0; r < 4; ++r) {
        int t = wr + ti * 16 + quad * 4 + r;
        Y[ti][tj][r] *= Dpow[t + 1];
      }
  __syncthreads();   // Bmid: everyone done reading KcA (Ktf)

  // masked decay-scaled A -> Abuf (aliases KcA)
#pragma unroll
  for (int ti = 0; ti < 2; ++ti)
#pragma unroll
    for (int tj = 0; tj < 2; ++tj)
#pragma unroll
      for (int r = 0; r < 4; ++r) {
        int t = wr + ti * 16 + quad * 4 + r;
        int s = wc + tj * 16 + li;
        float v = (t >= s) ? P[ti][tj][r] * Dpow[t - s] : 0.f;
        KcA[t * ST + s] = f2b(v);
      }
  __syncthreads();   // B2: Abuf visible

#pragma unroll
  for (int kk = 0; kk < 64; kk += 32) {
    bfrag aa0 = *(const bfrag*)&KcA[(wr + li) * ST + kk + quad * 8];
    bfrag aa1 = *(const bfrag*)&KcA[(wr + 16 + li) * ST + kk + quad * 8];
    bfrag vb0 = *(const bfrag*)&Vt[(wc + li) * ST + kk + quad * 8];
    bfrag vb1 = *(const bfrag*)&Vt[(wc + 16 + li) * ST + kk + quad * 8];
    Y[0][0] = MFMA16(aa0, vb0, Y[0][0]);
    Y[0][1] = MFMA16(aa0, vb1, Y[0][1]);
    Y[1][0] = MFMA16(aa1, vb0, Y[1][0]);
    Y[1][1] = MFMA16(aa1, vb1, Y[1][1]);
  }

#pragma unroll
  for (int ti = 0; ti < 2; ++ti)
#pragma unroll
    for (int tj = 0; tj < 2; ++tj)
#pragma unroll
      for (int r = 0; r < 4; ++r) {
        int t = wr + ti * 16 + quad * 4 + r;
        int e = wc + tj * 16 + li;
        yws[((size_t)(bb * 2048 + ch * 64 + t)) * 1024 + h * 64 + e] = f2b(Y[ti][tj][r]);
      }
}

// ---------------------------------------------------------------------------
// K3: y = Y_rwkv @ Wo^T, M=8192, N=1024, K=1024.
// ROUND-11: same m97 128x128 recipe as k1. Grid 512 = 64 m-tiles x 8
// n-tiles -> 2 blocks/CU resident (vs 1 before: its barrier stalls had
// ZERO cross-block cover). 8 m-tiles per XCD, m fastest.
// ---------------------------------------------------------------------------
__global__ __launch_bounds__(256, 4) void k3_out(
    const u16* __restrict__ yb, const u16* __restrict__ wob, float* __restrict__ out)
{
  __shared__ u16 As[2][128 * 32];
  __shared__ u16 Bs[2][128 * 32];
  const int tid  = threadIdx.x;
  const int wave = tid >> 6, lane = tid & 63;
  const int li = lane & 15, quad = lane >> 4;
  const int wm = (wave >> 1) * 64, wn = (wave & 1) * 64;

  const int bid = blockIdx.x;
  const int xcd = bid & 7, j = bid >> 3;            // j in [0,64)
  const int m0 = ((xcd << 3) | (j & 7)) * 128;      // 64 m-tiles, 8 per XCD
  const int n0 = (j >> 3) * 128;                    // 8 n-tiles

  ffrag acc[4][4];
#pragma unroll
  for (int i = 0; i < 4; ++i)
#pragma unroll
    for (int jj = 0; jj < 4; ++jj)
#pragma unroll
      for (int r = 0; r < 4; ++r) acc[i][jj][r] = 0.f;

  const int sr = lane >> 2, sc = (lane & 3) * 8;
  const u16* ga0 = yb  + (size_t)(m0 + wave * 32 + sr) * 1024 + sc;
  const u16* gb0 = wob + (size_t)(n0 + wave * 32 + sr) * 1024 + sc;

#define STG(IT, BF) do { \
    const u16* ga_ = ga0 + (IT) * 32; \
    const u16* gb_ = gb0 + (IT) * 32; \
    GLL16(ga_,             As[BF] + wave * 1024); \
    GLL16(ga_ + 16 * 1024, As[BF] + wave * 1024 + 512); \
    GLL16(gb_,             Bs[BF] + wave * 1024); \
    GLL16(gb_ + 16 * 1024, Bs[BF] + wave * 1024 + 512); \
  } while (0)

  STG(0, 0);

  for (int it = 0; it < 32; ++it) {
    __syncthreads();
    if (it + 1 < 32) STG(it + 1, (it + 1) & 1);

    const int cb = it & 1;
    bfrag av[4], bv[4];
#pragma unroll
    for (int i = 0; i < 4; ++i)  av[i]  = *(const bfrag*)&As[cb][(wm + i * 16 + li) * 32 + quad * 8];
#pragma unroll
    for (int jj = 0; jj < 4; ++jj) bv[jj] = *(const bfrag*)&Bs[cb][(wn + jj * 16 + li) * 32 + quad * 8];
#pragma unroll
    for (int i = 0; i < 4; ++i)
#pragma unroll
      for (int jj = 0; jj < 4; ++jj)
        acc[i][jj] = MFMA16(av[i], bv[jj], acc[i][jj]);
  }
#undef STG

#pragma unroll
  for (int i = 0; i < 4; ++i)
#pragma unroll
    for (int jj = 0; jj < 4; ++jj)
#pragma unroll
      for (int r = 0; r < 4; ++r) {
        int m = m0 + wm + i * 16 + quad * 4 + r;
        int n = n0 + wn + jj * 16 + li;
        out[(size_t)m * 1024 + n] = acc[i][jj][r];
      }
}

// ---------------------------------------------------------------------------
// Workspace layout (u16 elements):
//   xb   @ 0          (8388608)   -- reused as yws after K1
//   wb   @ 8388608    (3145728)
//   wob  @ 11534336   (1048576)
//   kws  @ 12582912   (8388608)   (B,H,L,HD) k*tf
//   vws  @ 20971520   (8388608)
//   rws  @ 29360128   (8388608)   sigmoid applied
//   ut   @ 37748736   (8388608)   U^T per (bh,chunk), bf16
//   sbf  @ 54525952   (8388608)   S^T per (bh,chunk), bf16
// ---------------------------------------------------------------------------
extern "C" void kernel_launch(void* const* d_in, const int* in_sizes, int n_in,
                              void* d_out, int out_size, void* d_ws, size_t ws_size,
                              hipStream_t stream) {
  const float* x  = (const float*)d_in[0];
  const float* Wk = (const float*)d_in[1];
  const float* Wv = (const float*)d_in[2];
  const float* Wr = (const float*)d_in[3];
  const float* Wo = (const float*)d_in[4];
  const float* td = (const float*)d_in[5];
  const float* tf = (const float*)d_in[6];
  float* out = (float*)d_out;

  u16* ws  = (u16*)d_ws;
  u16* xb  = ws;
  u16* wb  = ws + 8388608;
  u16* wob = ws + 11534336;
  u16* kws = ws + 12582912;
  u16* vws = ws + 20971520;
  u16* rws = ws + 29360128;
  u16* ut  = ws + 37748736;
  u16* sbf = ws + 54525952;
  u16* yws = xb;   // xb dead after K1

  hipLaunchKernelGGL(cvt_all, dim3(12288), dim3(256), 0, stream,
                     x, Wk, Wv, Wr, Wo, xb, wb, wob);
  hipLaunchKernelGGL(k1_proj, dim3(1536), dim3(256), 0, stream,
                     xb, wb, tf, kws, vws, rws);
  hipLaunchKernelGGL(k2a_u, dim3(2048), dim3(256), 0, stream,
                     kws, vws, td, ut);
  hipLaunchKernelGGL(k2b_scan, dim3(1024), dim3(256), 0, stream,
                     ut, td, sbf, out + 8388608);
  hipLaunchKernelGGL(k2c_y, dim3(2048), dim3(256), 0, stream,
                     kws, vws, rws, sbf, td, yws);
  hipLaunchKernelGGL(k3_out, dim3(512), dim3(256), 0, stream,
                     yws, wob, out);
}